// Round 3
// baseline (380.822 us; speedup 1.0000x reference)
//
#include <hip/hip_runtime.h>
#include <hip/hip_bf16.h>

typedef unsigned short u16;
typedef __attribute__((ext_vector_type(8))) short bf16x8;
typedef __attribute__((ext_vector_type(4))) float f32x4;

#define FENCE asm volatile("" ::: "memory")
#define BARRIER() do { FENCE; __builtin_amdgcn_s_barrier(); FENCE; } while (0)
#define LGKM0 asm volatile("s_waitcnt lgkmcnt(0)" ::: "memory")

__device__ __forceinline__ u16 f2bf(float f) {
  union { float f; unsigned u; } a; a.f = f;
  unsigned r = a.u + 0x7fffu + ((a.u >> 16) & 1u);  // RNE
  return (u16)(r >> 16);
}

__device__ __forceinline__ u16 f2h(float f) {
  union { _Float16 h; u16 u; } c; c.h = (_Float16)f; return c.u;
}

// Stage one half-tile [128 rows][64 u16] (row stride ldg) into 16 KB of LDS.
// LDS dest is LINEAR (global_load_lds lands lane i at base+i*16B); the
// bank-conflict swizzle is applied by permuting the per-lane GLOBAL source
// chunk with the involution q = (c&7) ^ (row&7).  Row stride (128 B) is
// 0 mod 32 banks, so banks depend only on chunk position: XORing ALL 3
// chunk bits with row&7 makes each 8-lane run span all 8 chunk positions
// (all 32 banks); residual aliasing is 2 lanes/bank = free (m136).
__device__ __forceinline__ void stage_ht(const u16* __restrict__ g, int ldg,
                                         u16* __restrict__ s, int tid) {
  int lane = tid & 63, wave = tid >> 6;  // 8 waves
#pragma unroll
  for (int t = 0; t < 2; ++t) {
    int cbase = t * 512 + wave * 64;
    int c = cbase + lane;                        // chunk 0..1023 (16B each)
    int row = c >> 3;                            // 0..127
    int q = (c & 7) ^ (row & 7);                 // inverse swizzle (involution)
    __builtin_amdgcn_global_load_lds(
        (const __attribute__((address_space(1))) unsigned int*)(g + (long)row * ldg + (q << 3)),
        (__attribute__((address_space(3))) unsigned int*)(s + cbase * 8),
        16, 0, 0);
  }
}

// A-subtile reads: fills a[4][2] = m-frags (mh*4..+3) x ksteps 0..1 from the
// wave's A half-buffer.  Swizzled addressing matches stage_ht (row&7 == lrow&7
// since all other row terms are multiples of 8).
__device__ __forceinline__ void ld_a(const u16* __restrict__ Ah, int mh,
                                     int lrow, int quad, int sw, bf16x8 (&a)[4][2]) {
#pragma unroll
  for (int i = 0; i < 4; ++i) {
    int rb = (mh * 64 + i * 16 + lrow) * 64;
#pragma unroll
    for (int ks = 0; ks < 2; ++ks)
      a[i][ks] = *(const bf16x8*)&Ah[rb + (((ks * 4 + quad) ^ sw) << 3)];
  }
}

// B-subtile reads: fills bq[2][2] = n-frags (nh*2..+1) x ksteps.
__device__ __forceinline__ void ld_b(const u16* __restrict__ Bh, int wn1, int nh,
                                     int lrow, int quad, int sw, bf16x8 (&bq)[2][2]) {
#pragma unroll
  for (int j = 0; j < 2; ++j) {
    int rb = (wn1 * 64 + (nh * 2 + j) * 16 + lrow) * 64;
#pragma unroll
    for (int ks = 0; ks < 2; ++ks)
      bq[j][ks] = *(const bf16x8*)&Bh[rb + (((ks * 4 + quad) ^ sw) << 3)];
  }
}

// One C-quadrant: 16 MFMA (4 m-frags x 2 n-frags x 2 ksteps).
template <int MH, int NH>
__device__ __forceinline__ void mfma_q(bf16x8 (&a)[4][2], bf16x8 (&bq)[2][2],
                                       f32x4 (&acc)[8][4]) {
#pragma unroll
  for (int i = 0; i < 4; ++i)
#pragma unroll
    for (int j = 0; j < 2; ++j) {
      f32x4 c = acc[MH * 4 + i][NH * 2 + j];
      c = __builtin_amdgcn_mfma_f32_16x16x32_bf16(a[i][0], bq[j][0], c, 0, 0, 0);
      c = __builtin_amdgcn_mfma_f32_16x16x32_bf16(a[i][1], bq[j][1], c, 0, 0, 0);
      acc[MH * 4 + i][NH * 2 + j] = c;
    }
}

// 256x256-tile 8-phase K-loop (T3+T4+T2+T5).  8 waves = 2M x 4N; BK=64;
// double-buffered K-tiles; per phase: {ds_read subtile | stage 1 half-tile |
// barrier | lgkm(0) | setprio(1) 16xMFMA setprio(0) | barrier}.  Counted
// vmcnt(2) at K-tile boundaries (never 0 in steady state): stages at phases
// {0,1,2}=KT+1 rest, {3,4,5,6}=KT+2, {7}=KT+3.h0, so each boundary's
// vmcnt(2) exactly validates the 4 half-tiles about to be read while keeping
// 1 in flight.  vmcnt(0) only at the final pair's mid-boundary.
__device__ __forceinline__ void gemm256_core(
    const u16* __restrict__ Ab, const u16* __restrict__ Bb,
    int lda, int ldb, int K, int tid,
    u16* __restrict__ As, u16* __restrict__ Bs, f32x4 (&acc)[8][4]) {
  int wave = tid >> 6, lane = tid & 63;
  int wm = wave >> 2, wn = wave & 3, wn1 = wn & 1;
  int lrow = lane & 15, quad = lane >> 4;
  int sw = lrow & 7;                         // full 3-bit row XOR (conflict-free)
#pragma unroll
  for (int i = 0; i < 8; ++i)
#pragma unroll
    for (int j = 0; j < 4; ++j) acc[i][j] = (f32x4){0.f, 0.f, 0.f, 0.f};
  const u16* Ah0 = As + wm * 8192;          // buf0, wave's M-half
  const u16* Ah1 = As + (2 + wm) * 8192;    // buf1
  const u16* Bh0 = Bs + (wn >> 1) * 8192;   // buf0, wave's N-half
  const u16* Bh1 = Bs + (2 + (wn >> 1)) * 8192;
  int nkt = K >> 6, npair = nkt >> 1;
  // Prologue: KT0 (4 half-tiles) + A(KT1,h0) = 5 half-tiles / 10 loads.
  stage_ht(Ab, lda, As, tid);                         // A0 h0 -> buf0
  stage_ht(Ab + 128L * lda, lda, As + 8192, tid);     // A0 h1
  stage_ht(Bb, ldb, Bs, tid);                         // B0 h0
  stage_ht(Bb + 128L * ldb, ldb, Bs + 8192, tid);     // B0 h1
  stage_ht(Ab + 64, lda, As + 2 * 8192, tid);         // A1 h0 -> buf1
  bf16x8 a[4][2], bq0[2][2], bq1[2][2];
  for (int pr = 0; pr < npair; ++pr) {
    int kt1 = pr * 2 + 1, kt2 = kt1 + 1, kt3 = kt1 + 2;
    bool st2 = kt2 < nkt, st3 = kt3 < nkt;
    // ===== KT even (buf0) =====
    asm volatile("s_waitcnt vmcnt(2)" ::: "memory");  // KT-even fully landed
    BARRIER();
    // phase 0: Q(0,0)
    ld_a(Ah0, 0, lrow, quad, sw, a);
    ld_b(Bh0, wn1, 0, lrow, quad, sw, bq0);
    stage_ht(Ab + 128L * lda + kt1 * 64, lda, As + 3 * 8192, tid);  // A kt1 h1
    BARRIER(); LGKM0;
    __builtin_amdgcn_s_setprio(1); mfma_q<0, 0>(a, bq0, acc); __builtin_amdgcn_s_setprio(0);
    BARRIER();
    // phase 1: Q(0,1)
    ld_b(Bh0, wn1, 1, lrow, quad, sw, bq1);
    stage_ht(Bb + kt1 * 64, ldb, Bs + 2 * 8192, tid);               // B kt1 h0
    BARRIER(); LGKM0;
    __builtin_amdgcn_s_setprio(1); mfma_q<0, 1>(a, bq1, acc); __builtin_amdgcn_s_setprio(0);
    BARRIER();
    // phase 2: Q(1,1)
    ld_a(Ah0, 1, lrow, quad, sw, a);
    stage_ht(Bb + 128L * ldb + kt1 * 64, ldb, Bs + 3 * 8192, tid);  // B kt1 h1
    BARRIER(); LGKM0;
    __builtin_amdgcn_s_setprio(1); mfma_q<1, 1>(a, bq1, acc); __builtin_amdgcn_s_setprio(0);
    BARRIER();
    // phase 3: Q(1,0)   (buf0 reads done at phase-2 barrier -> restage ok)
    if (st2) stage_ht(Ab + kt2 * 64, lda, As, tid);                 // A kt2 h0
    BARRIER(); LGKM0;
    __builtin_amdgcn_s_setprio(1); mfma_q<1, 0>(a, bq0, acc); __builtin_amdgcn_s_setprio(0);
    BARRIER();
    // ===== KT odd (buf1) =====
    if (pr + 1 < npair) asm volatile("s_waitcnt vmcnt(2)" ::: "memory");
    else                asm volatile("s_waitcnt vmcnt(0)" ::: "memory");
    BARRIER();
    // phase 4: Q(0,0)
    ld_a(Ah1, 0, lrow, quad, sw, a);
    ld_b(Bh1, wn1, 0, lrow, quad, sw, bq0);
    if (st2) stage_ht(Ab + 128L * lda + kt2 * 64, lda, As + 8192, tid);  // A kt2 h1
    BARRIER(); LGKM0;
    __builtin_amdgcn_s_setprio(1); mfma_q<0, 0>(a, bq0, acc); __builtin_amdgcn_s_setprio(0);
    BARRIER();
    // phase 5: Q(0,1)
    ld_b(Bh1, wn1, 1, lrow, quad, sw, bq1);
    if (st2) stage_ht(Bb + kt2 * 64, ldb, Bs, tid);                      // B kt2 h0
    BARRIER(); LGKM0;
    __builtin_amdgcn_s_setprio(1); mfma_q<0, 1>(a, bq1, acc); __builtin_amdgcn_s_setprio(0);
    BARRIER();
    // phase 6: Q(1,1)
    ld_a(Ah1, 1, lrow, quad, sw, a);
    if (st2) stage_ht(Bb + 128L * ldb + kt2 * 64, ldb, Bs + 8192, tid);  // B kt2 h1
    BARRIER(); LGKM0;
    __builtin_amdgcn_s_setprio(1); mfma_q<1, 1>(a, bq1, acc); __builtin_amdgcn_s_setprio(0);
    BARRIER();
    // phase 7: Q(1,0)   (buf1 reads done at phase-6 barrier)
    if (st3) stage_ht(Ab + kt3 * 64, lda, As + 2 * 8192, tid);           // A kt3 h0
    BARRIER(); LGKM0;
    __builtin_amdgcn_s_setprio(1); mfma_q<1, 0>(a, bq0, acc); __builtin_amdgcn_s_setprio(0);
    BARRIER();
  }
}

// Transposed bf16 epilogue: write C^T[col][rowbase..+3] as one uint2 (4 bf16).
__device__ __forceinline__ void epi_trans_bf16(
    f32x4 (&acc)[8][4], u16* __restrict__ C, long cbase, int m0, int n0, int ldc,
    const float* __restrict__ bias, float scale, int wm, int wn, int lrow, int quad) {
#pragma unroll
  for (int mf = 0; mf < 8; ++mf) {
    int rowbase = m0 + wm * 128 + mf * 16 + quad * 4;
    float4 b4 = bias ? *(const float4*)&bias[rowbase] : make_float4(0.f, 0.f, 0.f, 0.f);
#pragma unroll
    for (int nf = 0; nf < 4; ++nf) {
      int col = n0 + wn * 64 + nf * 16 + lrow;
      f32x4 a = acc[mf][nf];
      uint2 o;
      o.x = (unsigned)f2bf(a[0] * scale + b4.x) | ((unsigned)f2bf(a[1] * scale + b4.y) << 16);
      o.y = (unsigned)f2bf(a[2] * scale + b4.z) | ((unsigned)f2bf(a[3] * scale + b4.w) << 16);
      *(uint2*)(C + cbase + (long)col * ldc + rowbase) = o;
    }
  }
}

// MODE: 0 = TRANS bf16 (attnV->aoT), 1 = natural fp16 (scores),
//       2 = natural fp32 + bias + residual (proj), 3 = merged QKV.
template <int MODE>
__global__ __launch_bounds__(512, 2) void gemm_kernel(
    const u16* __restrict__ Ag, const u16* __restrict__ Bg,
    void* __restrict__ C0, void* __restrict__ C1, void* __restrict__ C2,
    const float* __restrict__ bias0, const float* __restrict__ bias1,
    const float* __restrict__ bias2, const float* __restrict__ resid,
    int lda, int ldb, int ldc,
    long strideA, long strideB, long strideC, int K, float scale) {
  extern __shared__ u16 smem[];
  u16* As = smem;            // 4 x 8192 u16 (2 bufs x 2 halves) = 64 KB
  u16* Bs = smem + 32768;    // 64 KB
  int tid = threadIdx.x;
  int b = blockIdx.z;
  int m0 = blockIdx.y * 256, n0 = blockIdx.x * 256;
  const u16* Ab = Ag + (long)b * strideA + (long)m0 * lda;
  const u16* Bb = Bg + (long)b * strideB + (long)n0 * ldb;
  f32x4 acc[8][4];
  gemm256_core(Ab, Bb, lda, ldb, K, tid, As, Bs, acc);

  int wave = tid >> 6, lane = tid & 63;
  int wm = wave >> 2, wn = wave & 3;
  int lrow = lane & 15, quad = lane >> 4;
  long cbase = (long)b * strideC;

  if (MODE == 0) {
    epi_trans_bf16(acc, (u16*)C0, cbase, m0, n0, ldc, bias0, scale, wm, wn, lrow, quad);
  } else if (MODE == 1) {
#pragma unroll
    for (int mf = 0; mf < 8; ++mf)
#pragma unroll
      for (int r = 0; r < 4; ++r) {
        int row = m0 + wm * 128 + mf * 16 + quad * 4 + r;
#pragma unroll
        for (int nf = 0; nf < 4; ++nf) {
          int col = n0 + wn * 64 + nf * 16 + lrow;
          ((u16*)C0)[cbase + (long)row * ldc + col] = f2h(acc[mf][nf][r] * scale);
        }
      }
  } else if (MODE == 2) {
#pragma unroll
    for (int mf = 0; mf < 8; ++mf)
#pragma unroll
      for (int r = 0; r < 4; ++r) {
        int row = m0 + wm * 128 + mf * 16 + quad * 4 + r;
        float bv = bias0[row];
#pragma unroll
        for (int nf = 0; nf < 4; ++nf) {
          int col = n0 + wn * 64 + nf * 16 + lrow;
          long idx = cbase + (long)row * ldc + col;
          ((float*)C0)[idx] = acc[mf][nf][r] * scale + bv + resid[idx];
        }
      }
  } else {  // MODE 3: merged QKV. Segments of 512 A-rows: q (trans), k (trans), v (natural bf16)
    int seg = m0 >> 9;
    int ml = m0 & 511;
    if (seg == 0) {
      epi_trans_bf16(acc, (u16*)C0, cbase, ml, n0, 512, bias0, 1.f, wm, wn, lrow, quad);
    } else if (seg == 1) {
      epi_trans_bf16(acc, (u16*)C1, cbase, ml, n0, 512, bias1, 1.f, wm, wn, lrow, quad);
    } else {
#pragma unroll
      for (int mf = 0; mf < 8; ++mf)
#pragma unroll
        for (int r = 0; r < 4; ++r) {
          int row = ml + wm * 128 + mf * 16 + quad * 4 + r;
          float bv = bias2[row];
#pragma unroll
          for (int nf = 0; nf < 4; ++nf) {
            int col = n0 + wn * 64 + nf * 16 + lrow;
            ((u16*)C2)[cbase + (long)row * 1024 + col] = f2bf(acc[mf][nf][r] + bv);
          }
        }
    }
  }
}

// One block per (group, batch): 32 channels x 1024 tokens. Writes hn TOKEN-MAJOR.
__global__ __launch_bounds__(256) void groupnorm_kernel(
    const float* __restrict__ x, const float* __restrict__ gamma,
    const float* __restrict__ beta, u16* __restrict__ hnT) {
  int g = blockIdx.x, b = blockIdx.y;
  const float* xb = x + ((long)b * 512 + g * 32) * 1024;
  int tid = threadIdx.x;
  float s = 0.f, sq = 0.f;
  float4 vals[32];
#pragma unroll
  for (int j = 0; j < 32; ++j) {
    float4 v = *(const float4*)(xb + (long)j * 1024 + tid * 4);
    vals[j] = v;
    s += v.x + v.y + v.z + v.w;
    sq += v.x * v.x + v.y * v.y + v.z * v.z + v.w * v.w;
  }
#pragma unroll
  for (int off = 1; off < 64; off <<= 1) {
    s += __shfl_xor(s, off);
    sq += __shfl_xor(sq, off);
  }
  __shared__ float ls[4], lq[4];
  if ((tid & 63) == 0) { ls[tid >> 6] = s; lq[tid >> 6] = sq; }
  __syncthreads();
  float ts = ls[0] + ls[1] + ls[2] + ls[3];
  float tq = lq[0] + lq[1] + lq[2] + lq[3];
  float mean = ts * (1.f / 32768.f);
  float var = tq * (1.f / 32768.f) - mean * mean;
  float rstd = rsqrtf(var + 1e-6f);
  u16* hb = hnT + (long)b * (1024 * 512) + g * 32;
#pragma unroll
  for (int t = 0; t < 4; ++t) {
    u16 row[32];
#pragma unroll
    for (int j = 0; j < 32; ++j) {
      float xv = ((const float*)&vals[j])[t];
      row[j] = f2bf((xv - mean) * rstd * gamma[g * 32 + j] + beta[g * 32 + j]);
    }
    uint4* dst = (uint4*)(hb + (long)(tid * 4 + t) * 512);
    const uint4* src = (const uint4*)row;
    dst[0] = src[0]; dst[1] = src[1]; dst[2] = src[2]; dst[3] = src[3];
  }
}

// One block per score row (1024 fp16). Writes bf16 attn in place (full row).
__global__ __launch_bounds__(256) void softmax_kernel(u16* __restrict__ s) {
  long row = blockIdx.x;
  u16* sr = s + row * 1024;
  int tid = threadIdx.x;
  union { uint2 u; _Float16 h[4]; } c;
  c.u = *(const uint2*)(sr + tid * 4);
  float v0 = (float)c.h[0], v1 = (float)c.h[1], v2 = (float)c.h[2], v3 = (float)c.h[3];
  float m = fmaxf(fmaxf(v0, v1), fmaxf(v2, v3));
#pragma unroll
  for (int off = 1; off < 64; off <<= 1) m = fmaxf(m, __shfl_xor(m, off));
  __shared__ float lm[4], lsum[4];
  if ((tid & 63) == 0) lm[tid >> 6] = m;
  __syncthreads();
  float rowmax = fmaxf(fmaxf(lm[0], lm[1]), fmaxf(lm[2], lm[3]));
  float e0 = expf(v0 - rowmax), e1 = expf(v1 - rowmax);
  float e2 = expf(v2 - rowmax), e3 = expf(v3 - rowmax);
  float sum = e0 + e1 + e2 + e3;
#pragma unroll
  for (int off = 1; off < 64; off <<= 1) sum += __shfl_xor(sum, off);
  if ((tid & 63) == 0) lsum[tid >> 6] = sum;
  __syncthreads();
  float inv = 1.f / (lsum[0] + lsum[1] + lsum[2] + lsum[3]);
  uint2 o;
  o.x = (unsigned)f2bf(e0 * inv) | ((unsigned)f2bf(e1 * inv) << 16);
  o.y = (unsigned)f2bf(e2 * inv) | ((unsigned)f2bf(e3 * inv) << 16);
  *(uint2*)(sr + tid * 4) = o;
}

// Convert the 4 weight matrices (512x512 fp32) to bf16, packed contiguously.
__global__ __launch_bounds__(256) void convertw_kernel(
    const float* __restrict__ w0, const float* __restrict__ w1,
    const float* __restrict__ w2, const float* __restrict__ w3,
    u16* __restrict__ out) {
  int wsel = blockIdx.x >> 8;
  const float* src = wsel == 0 ? w0 : wsel == 1 ? w1 : wsel == 2 ? w2 : w3;
  int idx = ((blockIdx.x & 255) * 256 + threadIdx.x) * 4;
  float4 v = *(const float4*)(src + idx);
  uint2 o;
  o.x = (unsigned)f2bf(v.x) | ((unsigned)f2bf(v.y) << 16);
  o.y = (unsigned)f2bf(v.z) | ((unsigned)f2bf(v.w) << 16);
  *(uint2*)(out + (long)wsel * 262144 + idx) = o;
}

extern "C" void kernel_launch(void* const* d_in, const int* in_sizes, int n_in,
                              void* d_out, int out_size, void* d_ws, size_t ws_size,
                              hipStream_t stream) {
  const float* x     = (const float*)d_in[0];
  const float* gamma = (const float*)d_in[1];
  const float* beta  = (const float*)d_in[2];
  const float* wq    = (const float*)d_in[3];
  const float* bq    = (const float*)d_in[4];
  const float* wk    = (const float*)d_in[5];
  const float* bk    = (const float*)d_in[6];
  const float* wv    = (const float*)d_in[7];
  const float* bv    = (const float*)d_in[8];
  const float* wp    = (const float*)d_in[9];
  const float* bp    = (const float*)d_in[10];
  float* out = (float*)d_out;
  char* ws = (char*)d_ws;

  // Allow 128 KiB dynamic LDS for the GEMM kernels (host-side, capture-safe).
  static int attr_done = 0;
  if (!attr_done) {
    hipFuncSetAttribute((const void*)gemm_kernel<0>, hipFuncAttributeMaxDynamicSharedMemorySize, 131072);
    hipFuncSetAttribute((const void*)gemm_kernel<1>, hipFuncAttributeMaxDynamicSharedMemorySize, 131072);
    hipFuncSetAttribute((const void*)gemm_kernel<2>, hipFuncAttributeMaxDynamicSharedMemorySize, 131072);
    hipFuncSetAttribute((const void*)gemm_kernel<3>, hipFuncAttributeMaxDynamicSharedMemorySize, 131072);
    attr_done = 1;
  }

  // Workspace (194 MB)
  u16* wbf = (u16*)ws;                      //   2 MB: wq|wk|wv|wp bf16 [o][c], packed
  u16* hnT = (u16*)(ws + (2L << 20));       //  32 MB: [b][n][c]  (reused for aoT)
  u16* qT  = (u16*)(ws + (34L << 20));      //  32 MB: [b][n][c]
  u16* kT  = (u16*)(ws + (66L << 20));      //  32 MB: [b][m][c]
  u16* v   = (u16*)(ws + (98L << 20));      //  32 MB: [b][c][m]
  u16* s16 = (u16*)(ws + (130L << 20));     //  64 MB: [b][n][m] fp16 scores / bf16 attn
  u16* aoT = hnT;

  const long SB = 512L * 1024;        // per-batch element stride of 512x1024 tensors
  const long SS = 1024L * 1024;       // per-batch element stride of scores (u16)
  const float scale = 0.044194173824159216f;  // 512^-0.5

  convertw_kernel<<<1024, 256, 0, stream>>>(wq, wk, wv, wp, wbf);
  groupnorm_kernel<<<dim3(16, 32), 256, 0, stream>>>(x, gamma, beta, hnT);

  // Merged QKV: A = [wq;wk;wv] (1536x512), B = hnT [n][c]. q,k -> token-major; v natural.
  gemm_kernel<3><<<dim3(4, 6, 32), 512, 131072, stream>>>(
      wbf, hnT, qT, kT, v, bq, bk, bv, nullptr,
      512, 512, 0, 0, SB, SB, 512, 1.f);

  // Scores: s[n][m] = qT[n][:] . kT[m][:] * scale -> fp16, full (no chunking).
  gemm_kernel<1><<<dim3(4, 4, 32), 512, 131072, stream>>>(
      qT, kT, s16, nullptr, nullptr, nullptr, nullptr, nullptr, nullptr,
      512, 512, 1024, SB, SB, SS, 512, scale);

  softmax_kernel<<<32 * 1024, 256, 0, stream>>>(s16);

  // attn-V: aoT[n][c] = sum_m v[c][m] attn[n][m] (A = v, B = attn bf16 ld 1024).
  gemm_kernel<0><<<dim3(4, 2, 32), 512, 131072, stream>>>(
      v, s16, aoT, nullptr, nullptr, nullptr, nullptr, nullptr, nullptr,
      1024, 1024, 512, SB, SS, SB, 1024, 1.f);

  // Proj + bias + residual -> fp32 d_out (natural [c][n]).
  gemm_kernel<2><<<dim3(4, 2, 32), 512, 131072, stream>>>(
      wbf + 3 * 262144, aoT, out, nullptr, nullptr, bp, nullptr, nullptr, x,
      512, 512, 1024, 0, SB, SB, 512, 1.f);
}

// Round 4
// 369.319 us; speedup vs baseline: 1.0311x; 1.0311x over previous
//
#include <hip/hip_runtime.h>
#include <hip/hip_bf16.h>

typedef unsigned short u16;
typedef __attribute__((ext_vector_type(8))) short bf16x8;
typedef __attribute__((ext_vector_type(4))) float f32x4;

#define FENCE asm volatile("" ::: "memory")
#define BARRIER() do { FENCE; __builtin_amdgcn_s_barrier(); FENCE; } while (0)
#define LGKM0 asm volatile("s_waitcnt lgkmcnt(0)" ::: "memory")

__device__ __forceinline__ u16 f2bf(float f) {
  union { float f; unsigned u; } a; a.f = f;
  unsigned r = a.u + 0x7fffu + ((a.u >> 16) & 1u);  // RNE
  return (u16)(r >> 16);
}

__device__ __forceinline__ u16 f2h(float f) {
  union { _Float16 h; u16 u; } c; c.h = (_Float16)f; return c.u;
}

// Stage one half-tile [128 rows][64 u16] (row stride ldg) into 16 KB of LDS.
// LDS dest is LINEAR (global_load_lds lands lane i at base+i*16B); the
// bank-conflict swizzle is applied by permuting the per-lane GLOBAL source
// chunk with the involution q = (c&7) ^ (row&7).  Row stride (128 B) is
// 0 mod 32 banks, so banks depend only on chunk position: XORing ALL 3
// chunk bits with row&7 makes each 8-lane run span all 8 chunk positions
// (all 32 banks); residual aliasing is 2 lanes/bank = free (m136).
__device__ __forceinline__ void stage_ht(const u16* __restrict__ g, int ldg,
                                         u16* __restrict__ s, int tid) {
  int lane = tid & 63, wave = tid >> 6;  // 8 waves
#pragma unroll
  for (int t = 0; t < 2; ++t) {
    int cbase = t * 512 + wave * 64;
    int c = cbase + lane;                        // chunk 0..1023 (16B each)
    int row = c >> 3;                            // 0..127
    int q = (c & 7) ^ (row & 7);                 // inverse swizzle (involution)
    __builtin_amdgcn_global_load_lds(
        (const __attribute__((address_space(1))) unsigned int*)(g + (long)row * ldg + (q << 3)),
        (__attribute__((address_space(3))) unsigned int*)(s + cbase * 8),
        16, 0, 0);
  }
}

// A-subtile reads: fills a[4][2] = m-frags (mh*4..+3) x ksteps 0..1 from the
// wave's A half-buffer.  Swizzled addressing matches stage_ht (row&7 == lrow&7
// since all other row terms are multiples of 8).
__device__ __forceinline__ void ld_a(const u16* __restrict__ Ah, int mh,
                                     int lrow, int quad, int sw, bf16x8 (&a)[4][2]) {
#pragma unroll
  for (int i = 0; i < 4; ++i) {
    int rb = (mh * 64 + i * 16 + lrow) * 64;
#pragma unroll
    for (int ks = 0; ks < 2; ++ks)
      a[i][ks] = *(const bf16x8*)&Ah[rb + (((ks * 4 + quad) ^ sw) << 3)];
  }
}

// B-subtile reads: fills bq[2][2] = n-frags (nh*2..+1) x ksteps.
__device__ __forceinline__ void ld_b(const u16* __restrict__ Bh, int wn1, int nh,
                                     int lrow, int quad, int sw, bf16x8 (&bq)[2][2]) {
#pragma unroll
  for (int j = 0; j < 2; ++j) {
    int rb = (wn1 * 64 + (nh * 2 + j) * 16 + lrow) * 64;
#pragma unroll
    for (int ks = 0; ks < 2; ++ks)
      bq[j][ks] = *(const bf16x8*)&Bh[rb + (((ks * 4 + quad) ^ sw) << 3)];
  }
}

// One C-quadrant: 16 MFMA (4 m-frags x 2 n-frags x 2 ksteps).
template <int MH, int NH>
__device__ __forceinline__ void mfma_q(bf16x8 (&a)[4][2], bf16x8 (&bq)[2][2],
                                       f32x4 (&acc)[8][4]) {
#pragma unroll
  for (int i = 0; i < 4; ++i)
#pragma unroll
    for (int j = 0; j < 2; ++j) {
      f32x4 c = acc[MH * 4 + i][NH * 2 + j];
      c = __builtin_amdgcn_mfma_f32_16x16x32_bf16(a[i][0], bq[j][0], c, 0, 0, 0);
      c = __builtin_amdgcn_mfma_f32_16x16x32_bf16(a[i][1], bq[j][1], c, 0, 0, 0);
      acc[MH * 4 + i][NH * 2 + j] = c;
    }
}

// 256x256-tile 8-phase K-loop, SINGLE barrier per phase.
// Per phase: { ds_read subtile | stage 1 half-tile | setprio(1) 16xMFMA
// setprio(0) | lgkmcnt(0) | barrier }.  The compiler inserts counted
// lgkmcnt before the MFMAs (ds_read->MFMA dep); the explicit lgkmcnt(0)
// before the barrier guarantees each wave's LDS reads are SERVICED before
// it passes the barrier, which is the only thing the WAR guard (stage
// overwriting a previously-read region, issued in a later phase) needs.
// Dropping the pre-MFMA barrier lets skewed waves overlap LDS reads with
// MFMA across the 2 waves/SIMD instead of hard-serializing {all-read}
// then {all-MFMA}.
// Counted vmcnt(2) at K-tile boundaries (never 0 in steady state): stages
// at phases {0,1,2}=KT+1 rest, {3,4,5,6}=KT+2, {7}=KT+3.h0, so each
// boundary's vmcnt(2) exactly validates the 4 half-tiles about to be read
// while keeping 1 in flight.  vmcnt(0) only at the final pair's mid-boundary.
__device__ __forceinline__ void gemm256_core(
    const u16* __restrict__ Ab, const u16* __restrict__ Bb,
    int lda, int ldb, int K, int tid,
    u16* __restrict__ As, u16* __restrict__ Bs, f32x4 (&acc)[8][4]) {
  int wave = tid >> 6, lane = tid & 63;
  int wm = wave >> 2, wn = wave & 3, wn1 = wn & 1;
  int lrow = lane & 15, quad = lane >> 4;
  int sw = lrow & 7;                         // full 3-bit row XOR (conflict-free)
#pragma unroll
  for (int i = 0; i < 8; ++i)
#pragma unroll
    for (int j = 0; j < 4; ++j) acc[i][j] = (f32x4){0.f, 0.f, 0.f, 0.f};
  const u16* Ah0 = As + wm * 8192;          // buf0, wave's M-half
  const u16* Ah1 = As + (2 + wm) * 8192;    // buf1
  const u16* Bh0 = Bs + (wn >> 1) * 8192;   // buf0, wave's N-half
  const u16* Bh1 = Bs + (2 + (wn >> 1)) * 8192;
  int nkt = K >> 6, npair = nkt >> 1;
  // Prologue: KT0 (4 half-tiles) + A(KT1,h0) = 5 half-tiles / 10 loads.
  stage_ht(Ab, lda, As, tid);                         // A0 h0 -> buf0
  stage_ht(Ab + 128L * lda, lda, As + 8192, tid);     // A0 h1
  stage_ht(Bb, ldb, Bs, tid);                         // B0 h0
  stage_ht(Bb + 128L * ldb, ldb, Bs + 8192, tid);     // B0 h1
  stage_ht(Ab + 64, lda, As + 2 * 8192, tid);         // A1 h0 -> buf1
  bf16x8 a[4][2], bq0[2][2], bq1[2][2];
  for (int pr = 0; pr < npair; ++pr) {
    int kt1 = pr * 2 + 1, kt2 = kt1 + 1, kt3 = kt1 + 2;
    bool st2 = kt2 < nkt, st3 = kt3 < nkt;
    // ===== KT even (buf0) =====
    asm volatile("s_waitcnt vmcnt(2)" ::: "memory");  // KT-even fully landed
    BARRIER();
    // phase 0: Q(0,0)
    ld_a(Ah0, 0, lrow, quad, sw, a);
    ld_b(Bh0, wn1, 0, lrow, quad, sw, bq0);
    stage_ht(Ab + 128L * lda + kt1 * 64, lda, As + 3 * 8192, tid);  // A kt1 h1
    __builtin_amdgcn_s_setprio(1); mfma_q<0, 0>(a, bq0, acc); __builtin_amdgcn_s_setprio(0);
    LGKM0; BARRIER();
    // phase 1: Q(0,1)
    ld_b(Bh0, wn1, 1, lrow, quad, sw, bq1);
    stage_ht(Bb + kt1 * 64, ldb, Bs + 2 * 8192, tid);               // B kt1 h0
    __builtin_amdgcn_s_setprio(1); mfma_q<0, 1>(a, bq1, acc); __builtin_amdgcn_s_setprio(0);
    LGKM0; BARRIER();
    // phase 2: Q(1,1)
    ld_a(Ah0, 1, lrow, quad, sw, a);
    stage_ht(Bb + 128L * ldb + kt1 * 64, ldb, Bs + 3 * 8192, tid);  // B kt1 h1
    __builtin_amdgcn_s_setprio(1); mfma_q<1, 1>(a, bq1, acc); __builtin_amdgcn_s_setprio(0);
    LGKM0; BARRIER();
    // phase 3: Q(1,0)   (buf0-A reads serviced before phase-2 barrier -> restage ok)
    if (st2) stage_ht(Ab + kt2 * 64, lda, As, tid);                 // A kt2 h0
    __builtin_amdgcn_s_setprio(1); mfma_q<1, 0>(a, bq0, acc); __builtin_amdgcn_s_setprio(0);
    LGKM0;
    // ===== KT odd (buf1) =====
    if (pr + 1 < npair) asm volatile("s_waitcnt vmcnt(2)" ::: "memory");
    else                asm volatile("s_waitcnt vmcnt(0)" ::: "memory");
    BARRIER();
    // phase 4: Q(0,0)
    ld_a(Ah1, 0, lrow, quad, sw, a);
    ld_b(Bh1, wn1, 0, lrow, quad, sw, bq0);
    if (st2) stage_ht(Ab + 128L * lda + kt2 * 64, lda, As + 8192, tid);  // A kt2 h1
    __builtin_amdgcn_s_setprio(1); mfma_q<0, 0>(a, bq0, acc); __builtin_amdgcn_s_setprio(0);
    LGKM0; BARRIER();
    // phase 5: Q(0,1)
    ld_b(Bh1, wn1, 1, lrow, quad, sw, bq1);
    if (st2) stage_ht(Bb + kt2 * 64, ldb, Bs, tid);                      // B kt2 h0
    __builtin_amdgcn_s_setprio(1); mfma_q<0, 1>(a, bq1, acc); __builtin_amdgcn_s_setprio(0);
    LGKM0; BARRIER();
    // phase 6: Q(1,1)
    ld_a(Ah1, 1, lrow, quad, sw, a);
    if (st2) stage_ht(Bb + 128L * ldb + kt2 * 64, ldb, Bs + 8192, tid);  // B kt2 h1
    __builtin_amdgcn_s_setprio(1); mfma_q<1, 1>(a, bq1, acc); __builtin_amdgcn_s_setprio(0);
    LGKM0; BARRIER();
    // phase 7: Q(1,0)   (buf1-A reads serviced before phase-6 barrier)
    if (st3) stage_ht(Ab + kt3 * 64, lda, As + 2 * 8192, tid);           // A kt3 h0
    __builtin_amdgcn_s_setprio(1); mfma_q<1, 0>(a, bq0, acc); __builtin_amdgcn_s_setprio(0);
    LGKM0; BARRIER();
  }
}

// Transposed bf16 epilogue: write C^T[col][rowbase..+3] as one uint2 (4 bf16).
__device__ __forceinline__ void epi_trans_bf16(
    f32x4 (&acc)[8][4], u16* __restrict__ C, long cbase, int m0, int n0, int ldc,
    const float* __restrict__ bias, float scale, int wm, int wn, int lrow, int quad) {
#pragma unroll
  for (int mf = 0; mf < 8; ++mf) {
    int rowbase = m0 + wm * 128 + mf * 16 + quad * 4;
    float4 b4 = bias ? *(const float4*)&bias[rowbase] : make_float4(0.f, 0.f, 0.f, 0.f);
#pragma unroll
    for (int nf = 0; nf < 4; ++nf) {
      int col = n0 + wn * 64 + nf * 16 + lrow;
      f32x4 a = acc[mf][nf];
      uint2 o;
      o.x = (unsigned)f2bf(a[0] * scale + b4.x) | ((unsigned)f2bf(a[1] * scale + b4.y) << 16);
      o.y = (unsigned)f2bf(a[2] * scale + b4.z) | ((unsigned)f2bf(a[3] * scale + b4.w) << 16);
      *(uint2*)(C + cbase + (long)col * ldc + rowbase) = o;
    }
  }
}

// MODE: 0 = TRANS bf16 (attnV->aoT), 1 = natural fp16 (scores),
//       2 = natural fp32 + bias + residual (proj), 3 = merged QKV.
template <int MODE>
__global__ __launch_bounds__(512, 2) void gemm_kernel(
    const u16* __restrict__ Ag, const u16* __restrict__ Bg,
    void* __restrict__ C0, void* __restrict__ C1, void* __restrict__ C2,
    const float* __restrict__ bias0, const float* __restrict__ bias1,
    const float* __restrict__ bias2, const float* __restrict__ resid,
    int lda, int ldb, int ldc,
    long strideA, long strideB, long strideC, int K, float scale) {
  extern __shared__ u16 smem[];
  u16* As = smem;            // 4 x 8192 u16 (2 bufs x 2 halves) = 64 KB
  u16* Bs = smem + 32768;    // 64 KB
  int tid = threadIdx.x;
  int b = blockIdx.z;
  int m0 = blockIdx.y * 256, n0 = blockIdx.x * 256;
  const u16* Ab = Ag + (long)b * strideA + (long)m0 * lda;
  const u16* Bb = Bg + (long)b * strideB + (long)n0 * ldb;
  f32x4 acc[8][4];
  gemm256_core(Ab, Bb, lda, ldb, K, tid, As, Bs, acc);

  int wave = tid >> 6, lane = tid & 63;
  int wm = wave >> 2, wn = wave & 3;
  int lrow = lane & 15, quad = lane >> 4;
  long cbase = (long)b * strideC;

  if (MODE == 0) {
    epi_trans_bf16(acc, (u16*)C0, cbase, m0, n0, ldc, bias0, scale, wm, wn, lrow, quad);
  } else if (MODE == 1) {
#pragma unroll
    for (int mf = 0; mf < 8; ++mf)
#pragma unroll
      for (int r = 0; r < 4; ++r) {
        int row = m0 + wm * 128 + mf * 16 + quad * 4 + r;
#pragma unroll
        for (int nf = 0; nf < 4; ++nf) {
          int col = n0 + wn * 64 + nf * 16 + lrow;
          ((u16*)C0)[cbase + (long)row * ldc + col] = f2h(acc[mf][nf][r] * scale);
        }
      }
  } else if (MODE == 2) {
#pragma unroll
    for (int mf = 0; mf < 8; ++mf)
#pragma unroll
      for (int r = 0; r < 4; ++r) {
        int row = m0 + wm * 128 + mf * 16 + quad * 4 + r;
        float bv = bias0[row];
#pragma unroll
        for (int nf = 0; nf < 4; ++nf) {
          int col = n0 + wn * 64 + nf * 16 + lrow;
          long idx = cbase + (long)row * ldc + col;
          ((float*)C0)[idx] = acc[mf][nf][r] * scale + bv + resid[idx];
        }
      }
  } else {  // MODE 3: merged QKV. Segments of 512 A-rows: q (trans), k (trans), v (natural bf16)
    int seg = m0 >> 9;
    int ml = m0 & 511;
    if (seg == 0) {
      epi_trans_bf16(acc, (u16*)C0, cbase, ml, n0, 512, bias0, 1.f, wm, wn, lrow, quad);
    } else if (seg == 1) {
      epi_trans_bf16(acc, (u16*)C1, cbase, ml, n0, 512, bias1, 1.f, wm, wn, lrow, quad);
    } else {
#pragma unroll
      for (int mf = 0; mf < 8; ++mf)
#pragma unroll
        for (int r = 0; r < 4; ++r) {
          int row = ml + wm * 128 + mf * 16 + quad * 4 + r;
          float bv = bias2[row];
#pragma unroll
          for (int nf = 0; nf < 4; ++nf) {
            int col = n0 + wn * 64 + nf * 16 + lrow;
            ((u16*)C2)[cbase + (long)row * 1024 + col] = f2bf(acc[mf][nf][r] + bv);
          }
        }
    }
  }
}

// One block per (group, batch): 32 channels x 1024 tokens. Writes hn TOKEN-MAJOR.
__global__ __launch_bounds__(256) void groupnorm_kernel(
    const float* __restrict__ x, const float* __restrict__ gamma,
    const float* __restrict__ beta, u16* __restrict__ hnT) {
  int g = blockIdx.x, b = blockIdx.y;
  const float* xb = x + ((long)b * 512 + g * 32) * 1024;
  int tid = threadIdx.x;
  float s = 0.f, sq = 0.f;
  float4 vals[32];
#pragma unroll
  for (int j = 0; j < 32; ++j) {
    float4 v = *(const float4*)(xb + (long)j * 1024 + tid * 4);
    vals[j] = v;
    s += v.x + v.y + v.z + v.w;
    sq += v.x * v.x + v.y * v.y + v.z * v.z + v.w * v.w;
  }
#pragma unroll
  for (int off = 1; off < 64; off <<= 1) {
    s += __shfl_xor(s, off);
    sq += __shfl_xor(sq, off);
  }
  __shared__ float ls[4], lq[4];
  if ((tid & 63) == 0) { ls[tid >> 6] = s; lq[tid >> 6] = sq; }
  __syncthreads();
  float ts = ls[0] + ls[1] + ls[2] + ls[3];
  float tq = lq[0] + lq[1] + lq[2] + lq[3];
  float mean = ts * (1.f / 32768.f);
  float var = tq * (1.f / 32768.f) - mean * mean;
  float rstd = rsqrtf(var + 1e-6f);
  u16* hb = hnT + (long)b * (1024 * 512) + g * 32;
#pragma unroll
  for (int t = 0; t < 4; ++t) {
    u16 row[32];
#pragma unroll
    for (int j = 0; j < 32; ++j) {
      float xv = ((const float*)&vals[j])[t];
      row[j] = f2bf((xv - mean) * rstd * gamma[g * 32 + j] + beta[g * 32 + j]);
    }
    uint4* dst = (uint4*)(hb + (long)(tid * 4 + t) * 512);
    const uint4* src = (const uint4*)row;
    dst[0] = src[0]; dst[1] = src[1]; dst[2] = src[2]; dst[3] = src[3];
  }
}

// One block per score row (1024 fp16). Writes bf16 attn in place (full row).
__global__ __launch_bounds__(256) void softmax_kernel(u16* __restrict__ s) {
  long row = blockIdx.x;
  u16* sr = s + row * 1024;
  int tid = threadIdx.x;
  union { uint2 u; _Float16 h[4]; } c;
  c.u = *(const uint2*)(sr + tid * 4);
  float v0 = (float)c.h[0], v1 = (float)c.h[1], v2 = (float)c.h[2], v3 = (float)c.h[3];
  float m = fmaxf(fmaxf(v0, v1), fmaxf(v2, v3));
#pragma unroll
  for (int off = 1; off < 64; off <<= 1) m = fmaxf(m, __shfl_xor(m, off));
  __shared__ float lm[4], lsum[4];
  if ((tid & 63) == 0) lm[tid >> 6] = m;
  __syncthreads();
  float rowmax = fmaxf(fmaxf(lm[0], lm[1]), fmaxf(lm[2], lm[3]));
  float e0 = expf(v0 - rowmax), e1 = expf(v1 - rowmax);
  float e2 = expf(v2 - rowmax), e3 = expf(v3 - rowmax);
  float sum = e0 + e1 + e2 + e3;
#pragma unroll
  for (int off = 1; off < 64; off <<= 1) sum += __shfl_xor(sum, off);
  if ((tid & 63) == 0) lsum[tid >> 6] = sum;
  __syncthreads();
  float inv = 1.f / (lsum[0] + lsum[1] + lsum[2] + lsum[3]);
  uint2 o;
  o.x = (unsigned)f2bf(e0 * inv) | ((unsigned)f2bf(e1 * inv) << 16);
  o.y = (unsigned)f2bf(e2 * inv) | ((unsigned)f2bf(e3 * inv) << 16);
  *(uint2*)(sr + tid * 4) = o;
}

// Convert the 4 weight matrices (512x512 fp32) to bf16, packed contiguously.
__global__ __launch_bounds__(256) void convertw_kernel(
    const float* __restrict__ w0, const float* __restrict__ w1,
    const float* __restrict__ w2, const float* __restrict__ w3,
    u16* __restrict__ out) {
  int wsel = blockIdx.x >> 8;
  const float* src = wsel == 0 ? w0 : wsel == 1 ? w1 : wsel == 2 ? w2 : w3;
  int idx = ((blockIdx.x & 255) * 256 + threadIdx.x) * 4;
  float4 v = *(const float4*)(src + idx);
  uint2 o;
  o.x = (unsigned)f2bf(v.x) | ((unsigned)f2bf(v.y) << 16);
  o.y = (unsigned)f2bf(v.z) | ((unsigned)f2bf(v.w) << 16);
  *(uint2*)(out + (long)wsel * 262144 + idx) = o;
}

extern "C" void kernel_launch(void* const* d_in, const int* in_sizes, int n_in,
                              void* d_out, int out_size, void* d_ws, size_t ws_size,
                              hipStream_t stream) {
  const float* x     = (const float*)d_in[0];
  const float* gamma = (const float*)d_in[1];
  const float* beta  = (const float*)d_in[2];
  const float* wq    = (const float*)d_in[3];
  const float* bq    = (const float*)d_in[4];
  const float* wk    = (const float*)d_in[5];
  const float* bk    = (const float*)d_in[6];
  const float* wv    = (const float*)d_in[7];
  const float* bv    = (const float*)d_in[8];
  const float* wp    = (const float*)d_in[9];
  const float* bp    = (const float*)d_in[10];
  float* out = (float*)d_out;
  char* ws = (char*)d_ws;

  // Allow 128 KiB dynamic LDS for the GEMM kernels (host-side, capture-safe).
  static int attr_done = 0;
  if (!attr_done) {
    hipFuncSetAttribute((const void*)gemm_kernel<0>, hipFuncAttributeMaxDynamicSharedMemorySize, 131072);
    hipFuncSetAttribute((const void*)gemm_kernel<1>, hipFuncAttributeMaxDynamicSharedMemorySize, 131072);
    hipFuncSetAttribute((const void*)gemm_kernel<2>, hipFuncAttributeMaxDynamicSharedMemorySize, 131072);
    hipFuncSetAttribute((const void*)gemm_kernel<3>, hipFuncAttributeMaxDynamicSharedMemorySize, 131072);
    attr_done = 1;
  }

  // Workspace (194 MB)
  u16* wbf = (u16*)ws;                      //   2 MB: wq|wk|wv|wp bf16 [o][c], packed
  u16* hnT = (u16*)(ws + (2L << 20));       //  32 MB: [b][n][c]  (reused for aoT)
  u16* qT  = (u16*)(ws + (34L << 20));      //  32 MB: [b][n][c]
  u16* kT  = (u16*)(ws + (66L << 20));      //  32 MB: [b][m][c]
  u16* v   = (u16*)(ws + (98L << 20));      //  32 MB: [b][c][m]
  u16* s16 = (u16*)(ws + (130L << 20));     //  64 MB: [b][n][m] fp16 scores / bf16 attn
  u16* aoT = hnT;

  const long SB = 512L * 1024;        // per-batch element stride of 512x1024 tensors
  const long SS = 1024L * 1024;       // per-batch element stride of scores (u16)
  const float scale = 0.044194173824159216f;  // 512^-0.5

  convertw_kernel<<<1024, 256, 0, stream>>>(wq, wk, wv, wp, wbf);
  groupnorm_kernel<<<dim3(16, 32), 256, 0, stream>>>(x, gamma, beta, hnT);

  // Merged QKV: A = [wq;wk;wv] (1536x512), B = hnT [n][c]. q,k -> token-major; v natural.
  gemm_kernel<3><<<dim3(4, 6, 32), 512, 131072, stream>>>(
      wbf, hnT, qT, kT, v, bq, bk, bv, nullptr,
      512, 512, 0, 0, SB, SB, 512, 1.f);

  // Scores: s[n][m] = qT[n][:] . kT[m][:] * scale -> fp16, full (no chunking).
  gemm_kernel<1><<<dim3(4, 4, 32), 512, 131072, stream>>>(
      qT, kT, s16, nullptr, nullptr, nullptr, nullptr, nullptr, nullptr,
      512, 512, 1024, SB, SB, SS, 512, scale);

  softmax_kernel<<<32 * 1024, 256, 0, stream>>>(s16);

  // attn-V: aoT[n][c] = sum_m v[c][m] attn[n][m] (A = v, B = attn bf16 ld 1024).
  gemm_kernel<0><<<dim3(4, 2, 32), 512, 131072, stream>>>(
      v, s16, aoT, nullptr, nullptr, nullptr, nullptr, nullptr, nullptr,
      1024, 1024, 512, SB, SS, SB, 1024, 1.f);

  // Proj + bias + residual -> fp32 d_out (natural [c][n]).
  gemm_kernel<2><<<dim3(4, 2, 32), 512, 131072, stream>>>(
      wbf + 3 * 262144, aoT, out, nullptr, nullptr, bp, nullptr, nullptr, x,
      512, 512, 1024, 0, SB, SB, 512, 1.f);
}

// Round 5
// 362.524 us; speedup vs baseline: 1.0505x; 1.0187x over previous
//
#include <hip/hip_runtime.h>
#include <hip/hip_bf16.h>

typedef unsigned short u16;
typedef __attribute__((ext_vector_type(8))) short bf16x8;
typedef __attribute__((ext_vector_type(4))) float f32x4;

__device__ __forceinline__ u16 f2bf(float f) {
  union { float f; unsigned u; } a; a.f = f;
  unsigned r = a.u + 0x7fffu + ((a.u >> 16) & 1u);  // RNE
  return (u16)(r >> 16);
}

__device__ __forceinline__ u16 f2h(float f) {
  union { _Float16 h; u16 u; } c; c.h = (_Float16)f; return c.u;
}

// Stage one half-tile [128 rows][64 u16] (row stride ldg) into 16 KB of LDS.
// LDS dest is LINEAR (global_load_lds lands lane i at base+i*16B); the
// bank-conflict swizzle is applied by permuting the per-lane GLOBAL source
// chunk with the involution q = (c&7) ^ (row&7).  Row stride (128 B) is
// 0 mod 32 banks, so banks depend only on chunk position: XORing ALL 3
// chunk bits with row&7 makes each 8-lane run span all 8 chunk positions
// (all 32 banks); residual aliasing is 2 lanes/bank = free (m136).
__device__ __forceinline__ void stage_ht(const u16* __restrict__ g, int ldg,
                                         u16* __restrict__ s, int tid) {
  int lane = tid & 63, wave = tid >> 6;  // 8 waves
#pragma unroll
  for (int t = 0; t < 2; ++t) {
    int cbase = t * 512 + wave * 64;
    int c = cbase + lane;                        // chunk 0..1023 (16B each)
    int row = c >> 3;                            // 0..127
    int q = (c & 7) ^ (row & 7);                 // inverse swizzle (involution)
    __builtin_amdgcn_global_load_lds(
        (const __attribute__((address_space(1))) unsigned int*)(g + (long)row * ldg + (q << 3)),
        (__attribute__((address_space(3))) unsigned int*)(s + cbase * 8),
        16, 0, 0);
  }
}

// A-subtile reads: fills a[4][2] = m-frags (mh*4..+3) x ksteps 0..1 from the
// wave's A half-buffer.  Swizzled addressing matches stage_ht (row&7 == lrow&7
// since all other row terms are multiples of 8).
__device__ __forceinline__ void ld_a(const u16* __restrict__ Ah, int mh,
                                     int lrow, int quad, int sw, bf16x8 (&a)[4][2]) {
#pragma unroll
  for (int i = 0; i < 4; ++i) {
    int rb = (mh * 64 + i * 16 + lrow) * 64;
#pragma unroll
    for (int ks = 0; ks < 2; ++ks)
      a[i][ks] = *(const bf16x8*)&Ah[rb + (((ks * 4 + quad) ^ sw) << 3)];
  }
}

// B-subtile reads: fills bq[2][2] = n-frags (nh*2..+1) x ksteps.
__device__ __forceinline__ void ld_b(const u16* __restrict__ Bh, int wn1, int nh,
                                     int lrow, int quad, int sw, bf16x8 (&bq)[2][2]) {
#pragma unroll
  for (int j = 0; j < 2; ++j) {
    int rb = (wn1 * 64 + (nh * 2 + j) * 16 + lrow) * 64;
#pragma unroll
    for (int ks = 0; ks < 2; ++ks)
      bq[j][ks] = *(const bf16x8*)&Bh[rb + (((ks * 4 + quad) ^ sw) << 3)];
  }
}

// One C-quadrant: 16 MFMA (4 m-frags x 2 n-frags x 2 ksteps).
template <int MH, int NH>
__device__ __forceinline__ void mfma_q(bf16x8 (&a)[4][2], bf16x8 (&bq)[2][2],
                                       f32x4 (&acc)[8][4]) {
#pragma unroll
  for (int i = 0; i < 4; ++i)
#pragma unroll
    for (int j = 0; j < 2; ++j) {
      f32x4 c = acc[MH * 4 + i][NH * 2 + j];
      c = __builtin_amdgcn_mfma_f32_16x16x32_bf16(a[i][0], bq[j][0], c, 0, 0, 0);
      c = __builtin_amdgcn_mfma_f32_16x16x32_bf16(a[i][1], bq[j][1], c, 0, 0, 0);
      acc[MH * 4 + i][NH * 2 + j] = c;
    }
}

// 256x256-tile FLAT-KT K-loop: ONE __syncthreads per K-tile.
// Body kt: { sync (vmcnt0+lgkm0: buf[kt&1] valid, prev readers done) |
//   issue ALL 24 ds_reads of the KT + 4 stage half-tiles for kt+1 into
//   buf[kt&1^1] | 64 MFMA in reuse order Q00,Q01,Q11,Q10 }.
// No inline-asm waits: the compiler emits counted lgkmcnt per quadrant
// (Q00 waits only on a0+bq0; bq1/a1 reads hide under Q00's MFMA), which is
// the fine read||MFMA interleave the per-phase barrier structure destroyed.
// WAR on the staged buffer is guarded by the barrier itself: buf[kt+1&1]'s
// previous readers (body kt-1) had their reads consumed by MFMA (lgkm
// serviced) before reaching the barrier of body kt.  The vmcnt(0) inside
// __syncthreads drains stages issued a full body (~1000+ cyc) earlier, so
// it is cheap (unlike per-phase drain-0).
__device__ __forceinline__ void gemm256_core(
    const u16* __restrict__ Ab, const u16* __restrict__ Bb,
    int lda, int ldb, int K, int tid,
    u16* __restrict__ As, u16* __restrict__ Bs, f32x4 (&acc)[8][4]) {
  int wave = tid >> 6, lane = tid & 63;
  int wm = wave >> 2, wn = wave & 3, wn1 = wn & 1;
  int lrow = lane & 15, quad = lane >> 4;
  int sw = lrow & 7;                         // full 3-bit row XOR (conflict-free)
#pragma unroll
  for (int i = 0; i < 8; ++i)
#pragma unroll
    for (int j = 0; j < 4; ++j) acc[i][j] = (f32x4){0.f, 0.f, 0.f, 0.f};
  int nkt = K >> 6;
  // Prologue: stage KT0 (4 half-tiles) -> buf0.
  stage_ht(Ab, lda, As, tid);
  stage_ht(Ab + 128L * lda, lda, As + 8192, tid);
  stage_ht(Bb, ldb, Bs, tid);
  stage_ht(Bb + 128L * ldb, ldb, Bs + 8192, tid);
  for (int kt = 0; kt < nkt; ++kt) {
    __syncthreads();  // buf[kt&1] landed (vmcnt0); all prev readers done
    const u16* Ah = As + ((kt & 1) * 2 + wm) * 8192;
    const u16* Bh = Bs + ((kt & 1) * 2 + (wn >> 1)) * 8192;
    bf16x8 a0[4][2], a1[4][2], bq0[2][2], bq1[2][2];
    // Q00's operands first (critical path), then next-KT stages (early
    // issue -> full body of latency before next barrier's drain), then the
    // remaining reads whose latency hides under Q00.
    ld_a(Ah, 0, lrow, quad, sw, a0);
    ld_b(Bh, wn1, 0, lrow, quad, sw, bq0);
    if (kt + 1 < nkt) {
      long ko = (long)(kt + 1) * 64;
      int nb = ((kt & 1) ^ 1) * 2;
      stage_ht(Ab + ko, lda, As + nb * 8192, tid);
      stage_ht(Ab + 128L * lda + ko, lda, As + (nb + 1) * 8192, tid);
      stage_ht(Bb + ko, ldb, Bs + nb * 8192, tid);
      stage_ht(Bb + 128L * ldb + ko, ldb, Bs + (nb + 1) * 8192, tid);
    }
    ld_b(Bh, wn1, 1, lrow, quad, sw, bq1);
    ld_a(Ah, 1, lrow, quad, sw, a1);
    __builtin_amdgcn_s_setprio(1);
    mfma_q<0, 0>(a0, bq0, acc);
    mfma_q<0, 1>(a0, bq1, acc);
    mfma_q<1, 1>(a1, bq1, acc);
    mfma_q<1, 0>(a1, bq0, acc);
    __builtin_amdgcn_s_setprio(0);
  }
}

// Transposed bf16 epilogue: write C^T[col][rowbase..+3] as one uint2 (4 bf16).
__device__ __forceinline__ void epi_trans_bf16(
    f32x4 (&acc)[8][4], u16* __restrict__ C, long cbase, int m0, int n0, int ldc,
    const float* __restrict__ bias, float scale, int wm, int wn, int lrow, int quad) {
#pragma unroll
  for (int mf = 0; mf < 8; ++mf) {
    int rowbase = m0 + wm * 128 + mf * 16 + quad * 4;
    float4 b4 = bias ? *(const float4*)&bias[rowbase] : make_float4(0.f, 0.f, 0.f, 0.f);
#pragma unroll
    for (int nf = 0; nf < 4; ++nf) {
      int col = n0 + wn * 64 + nf * 16 + lrow;
      f32x4 a = acc[mf][nf];
      uint2 o;
      o.x = (unsigned)f2bf(a[0] * scale + b4.x) | ((unsigned)f2bf(a[1] * scale + b4.y) << 16);
      o.y = (unsigned)f2bf(a[2] * scale + b4.z) | ((unsigned)f2bf(a[3] * scale + b4.w) << 16);
      *(uint2*)(C + cbase + (long)col * ldc + rowbase) = o;
    }
  }
}

// MODE: 0 = TRANS bf16 (attnV->aoT), 1 = natural fp16 (scores),
//       2 = natural fp32 + bias + residual (proj), 3 = merged QKV.
template <int MODE>
__global__ __launch_bounds__(512, 2) void gemm_kernel(
    const u16* __restrict__ Ag, const u16* __restrict__ Bg,
    void* __restrict__ C0, void* __restrict__ C1, void* __restrict__ C2,
    const float* __restrict__ bias0, const float* __restrict__ bias1,
    const float* __restrict__ bias2, const float* __restrict__ resid,
    int lda, int ldb, int ldc,
    long strideA, long strideB, long strideC, int K, float scale) {
  extern __shared__ u16 smem[];
  u16* As = smem;            // 4 x 8192 u16 (2 bufs x 2 halves) = 64 KB
  u16* Bs = smem + 32768;    // 64 KB
  int tid = threadIdx.x;
  int b = blockIdx.z;
  int m0 = blockIdx.y * 256, n0 = blockIdx.x * 256;
  const u16* Ab = Ag + (long)b * strideA + (long)m0 * lda;
  const u16* Bb = Bg + (long)b * strideB + (long)n0 * ldb;
  f32x4 acc[8][4];
  gemm256_core(Ab, Bb, lda, ldb, K, tid, As, Bs, acc);

  int wave = tid >> 6, lane = tid & 63;
  int wm = wave >> 2, wn = wave & 3;
  int lrow = lane & 15, quad = lane >> 4;
  long cbase = (long)b * strideC;

  if (MODE == 0) {
    epi_trans_bf16(acc, (u16*)C0, cbase, m0, n0, ldc, bias0, scale, wm, wn, lrow, quad);
  } else if (MODE == 1) {
#pragma unroll
    for (int mf = 0; mf < 8; ++mf)
#pragma unroll
      for (int r = 0; r < 4; ++r) {
        int row = m0 + wm * 128 + mf * 16 + quad * 4 + r;
#pragma unroll
        for (int nf = 0; nf < 4; ++nf) {
          int col = n0 + wn * 64 + nf * 16 + lrow;
          ((u16*)C0)[cbase + (long)row * ldc + col] = f2h(acc[mf][nf][r] * scale);
        }
      }
  } else if (MODE == 2) {
#pragma unroll
    for (int mf = 0; mf < 8; ++mf)
#pragma unroll
      for (int r = 0; r < 4; ++r) {
        int row = m0 + wm * 128 + mf * 16 + quad * 4 + r;
        float bv = bias0[row];
#pragma unroll
        for (int nf = 0; nf < 4; ++nf) {
          int col = n0 + wn * 64 + nf * 16 + lrow;
          long idx = cbase + (long)row * ldc + col;
          ((float*)C0)[idx] = acc[mf][nf][r] * scale + bv + resid[idx];
        }
      }
  } else {  // MODE 3: merged QKV. Segments of 512 A-rows: q (trans), k (trans), v (natural bf16)
    int seg = m0 >> 9;
    int ml = m0 & 511;
    if (seg == 0) {
      epi_trans_bf16(acc, (u16*)C0, cbase, ml, n0, 512, bias0, 1.f, wm, wn, lrow, quad);
    } else if (seg == 1) {
      epi_trans_bf16(acc, (u16*)C1, cbase, ml, n0, 512, bias1, 1.f, wm, wn, lrow, quad);
    } else {
#pragma unroll
      for (int mf = 0; mf < 8; ++mf)
#pragma unroll
        for (int r = 0; r < 4; ++r) {
          int row = ml + wm * 128 + mf * 16 + quad * 4 + r;
          float bv = bias2[row];
#pragma unroll
          for (int nf = 0; nf < 4; ++nf) {
            int col = n0 + wn * 64 + nf * 16 + lrow;
            ((u16*)C2)[cbase + (long)row * 1024 + col] = f2bf(acc[mf][nf][r] + bv);
          }
        }
    }
  }
}

// One block per (group, batch): 32 channels x 1024 tokens. Writes hn TOKEN-MAJOR.
__global__ __launch_bounds__(256) void groupnorm_kernel(
    const float* __restrict__ x, const float* __restrict__ gamma,
    const float* __restrict__ beta, u16* __restrict__ hnT) {
  int g = blockIdx.x, b = blockIdx.y;
  const float* xb = x + ((long)b * 512 + g * 32) * 1024;
  int tid = threadIdx.x;
  float s = 0.f, sq = 0.f;
  float4 vals[32];
#pragma unroll
  for (int j = 0; j < 32; ++j) {
    float4 v = *(const float4*)(xb + (long)j * 1024 + tid * 4);
    vals[j] = v;
    s += v.x + v.y + v.z + v.w;
    sq += v.x * v.x + v.y * v.y + v.z * v.z + v.w * v.w;
  }
#pragma unroll
  for (int off = 1; off < 64; off <<= 1) {
    s += __shfl_xor(s, off);
    sq += __shfl_xor(sq, off);
  }
  __shared__ float ls[4], lq[4];
  if ((tid & 63) == 0) { ls[tid >> 6] = s; lq[tid >> 6] = sq; }
  __syncthreads();
  float ts = ls[0] + ls[1] + ls[2] + ls[3];
  float tq = lq[0] + lq[1] + lq[2] + lq[3];
  float mean = ts * (1.f / 32768.f);
  float var = tq * (1.f / 32768.f) - mean * mean;
  float rstd = rsqrtf(var + 1e-6f);
  u16* hb = hnT + (long)b * (1024 * 512) + g * 32;
#pragma unroll
  for (int t = 0; t < 4; ++t) {
    u16 row[32];
#pragma unroll
    for (int j = 0; j < 32; ++j) {
      float xv = ((const float*)&vals[j])[t];
      row[j] = f2bf((xv - mean) * rstd * gamma[g * 32 + j] + beta[g * 32 + j]);
    }
    uint4* dst = (uint4*)(hb + (long)(tid * 4 + t) * 512);
    const uint4* src = (const uint4*)row;
    dst[0] = src[0]; dst[1] = src[1]; dst[2] = src[2]; dst[3] = src[3];
  }
}

// One block per score row (1024 fp16). Writes bf16 attn in place (full row).
__global__ __launch_bounds__(256) void softmax_kernel(u16* __restrict__ s) {
  long row = blockIdx.x;
  u16* sr = s + row * 1024;
  int tid = threadIdx.x;
  union { uint2 u; _Float16 h[4]; } c;
  c.u = *(const uint2*)(sr + tid * 4);
  float v0 = (float)c.h[0], v1 = (float)c.h[1], v2 = (float)c.h[2], v3 = (float)c.h[3];
  float m = fmaxf(fmaxf(v0, v1), fmaxf(v2, v3));
#pragma unroll
  for (int off = 1; off < 64; off <<= 1) m = fmaxf(m, __shfl_xor(m, off));
  __shared__ float lm[4], lsum[4];
  if ((tid & 63) == 0) lm[tid >> 6] = m;
  __syncthreads();
  float rowmax = fmaxf(fmaxf(lm[0], lm[1]), fmaxf(lm[2], lm[3]));
  float e0 = expf(v0 - rowmax), e1 = expf(v1 - rowmax);
  float e2 = expf(v2 - rowmax), e3 = expf(v3 - rowmax);
  float sum = e0 + e1 + e2 + e3;
#pragma unroll
  for (int off = 1; off < 64; off <<= 1) sum += __shfl_xor(sum, off);
  if ((tid & 63) == 0) lsum[tid >> 6] = sum;
  __syncthreads();
  float inv = 1.f / (lsum[0] + lsum[1] + lsum[2] + lsum[3]);
  uint2 o;
  o.x = (unsigned)f2bf(e0 * inv) | ((unsigned)f2bf(e1 * inv) << 16);
  o.y = (unsigned)f2bf(e2 * inv) | ((unsigned)f2bf(e3 * inv) << 16);
  *(uint2*)(sr + tid * 4) = o;
}

// Convert the 4 weight matrices (512x512 fp32) to bf16, packed contiguously.
__global__ __launch_bounds__(256) void convertw_kernel(
    const float* __restrict__ w0, const float* __restrict__ w1,
    const float* __restrict__ w2, const float* __restrict__ w3,
    u16* __restrict__ out) {
  int wsel = blockIdx.x >> 8;
  const float* src = wsel == 0 ? w0 : wsel == 1 ? w1 : wsel == 2 ? w2 : w3;
  int idx = ((blockIdx.x & 255) * 256 + threadIdx.x) * 4;
  float4 v = *(const float4*)(src + idx);
  uint2 o;
  o.x = (unsigned)f2bf(v.x) | ((unsigned)f2bf(v.y) << 16);
  o.y = (unsigned)f2bf(v.z) | ((unsigned)f2bf(v.w) << 16);
  *(uint2*)(out + (long)wsel * 262144 + idx) = o;
}

extern "C" void kernel_launch(void* const* d_in, const int* in_sizes, int n_in,
                              void* d_out, int out_size, void* d_ws, size_t ws_size,
                              hipStream_t stream) {
  const float* x     = (const float*)d_in[0];
  const float* gamma = (const float*)d_in[1];
  const float* beta  = (const float*)d_in[2];
  const float* wq    = (const float*)d_in[3];
  const float* bq    = (const float*)d_in[4];
  const float* wk    = (const float*)d_in[5];
  const float* bk    = (const float*)d_in[6];
  const float* wv    = (const float*)d_in[7];
  const float* bv    = (const float*)d_in[8];
  const float* wp    = (const float*)d_in[9];
  const float* bp    = (const float*)d_in[10];
  float* out = (float*)d_out;
  char* ws = (char*)d_ws;

  // Allow 128 KiB dynamic LDS for the GEMM kernels (host-side, capture-safe).
  static int attr_done = 0;
  if (!attr_done) {
    hipFuncSetAttribute((const void*)gemm_kernel<0>, hipFuncAttributeMaxDynamicSharedMemorySize, 131072);
    hipFuncSetAttribute((const void*)gemm_kernel<1>, hipFuncAttributeMaxDynamicSharedMemorySize, 131072);
    hipFuncSetAttribute((const void*)gemm_kernel<2>, hipFuncAttributeMaxDynamicSharedMemorySize, 131072);
    hipFuncSetAttribute((const void*)gemm_kernel<3>, hipFuncAttributeMaxDynamicSharedMemorySize, 131072);
    attr_done = 1;
  }

  // Workspace (194 MB)
  u16* wbf = (u16*)ws;                      //   2 MB: wq|wk|wv|wp bf16 [o][c], packed
  u16* hnT = (u16*)(ws + (2L << 20));       //  32 MB: [b][n][c]  (reused for aoT)
  u16* qT  = (u16*)(ws + (34L << 20));      //  32 MB: [b][n][c]
  u16* kT  = (u16*)(ws + (66L << 20));      //  32 MB: [b][m][c]
  u16* v   = (u16*)(ws + (98L << 20));      //  32 MB: [b][c][m]
  u16* s16 = (u16*)(ws + (130L << 20));     //  64 MB: [b][n][m] fp16 scores / bf16 attn
  u16* aoT = hnT;

  const long SB = 512L * 1024;        // per-batch element stride of 512x1024 tensors
  const long SS = 1024L * 1024;       // per-batch element stride of scores (u16)
  const float scale = 0.044194173824159216f;  // 512^-0.5

  convertw_kernel<<<1024, 256, 0, stream>>>(wq, wk, wv, wp, wbf);
  groupnorm_kernel<<<dim3(16, 32), 256, 0, stream>>>(x, gamma, beta, hnT);

  // Merged QKV: A = [wq;wk;wv] (1536x512), B = hnT [n][c]. q,k -> token-major; v natural.
  gemm_kernel<3><<<dim3(4, 6, 32), 512, 131072, stream>>>(
      wbf, hnT, qT, kT, v, bq, bk, bv, nullptr,
      512, 512, 0, 0, SB, SB, 512, 1.f);

  // Scores: s[n][m] = qT[n][:] . kT[m][:] * scale -> fp16, full (no chunking).
  gemm_kernel<1><<<dim3(4, 4, 32), 512, 131072, stream>>>(
      qT, kT, s16, nullptr, nullptr, nullptr, nullptr, nullptr, nullptr,
      512, 512, 1024, SB, SB, SS, 512, scale);

  softmax_kernel<<<32 * 1024, 256, 0, stream>>>(s16);

  // attn-V: aoT[n][c] = sum_m v[c][m] attn[n][m] (A = v, B = attn bf16 ld 1024).
  gemm_kernel<0><<<dim3(4, 2, 32), 512, 131072, stream>>>(
      v, s16, aoT, nullptr, nullptr, nullptr, nullptr, nullptr, nullptr,
      1024, 1024, 512, SB, SS, SB, 1024, 1.f);

  // Proj + bias + residual -> fp32 d_out (natural [c][n]).
  gemm_kernel<2><<<dim3(4, 2, 32), 512, 131072, stream>>>(
      wbf + 3 * 262144, aoT, out, nullptr, nullptr, bp, nullptr, nullptr, x,
      512, 512, 1024, 0, SB, SB, 512, 1.f);
}